// Round 2
// baseline (382.332 us; speedup 1.0000x reference)
//
#include <hip/hip_runtime.h>

// Problem constants (setup_inputs: B=2, N=256, D=256, H=8, LEN=516)
#define NPAIR 131072   // B*N*N
#define NDIM  256      // D
#define NH    8        // heads
#define NN    256      // N (k-dimension for topk / ind)
#define NROWS 512      // B*N rows for topk
#define LEN   516      // 2*D + 4
#define EPSV  1e-8f

__device__ __forceinline__ float dot4(float4 a, float4 b) {
    return fmaf(a.x, b.x, fmaf(a.y, b.y, fmaf(a.z, b.z, a.w * b.w)));
}

// Kernel 1: one LANE per (b,q,k) pair; one wave (=workgroup) per 64 pairs.
// Q/K are staged through XOR-swizzled LDS in 32-dim chunks so global loads
// stay coalesced while each lane reads its own pair's chunk conflict-free.
// W operands are wave-uniform -> scalar loads (s_load), no VALU cost.
// No cross-lane reductions at all.
__global__ __launch_bounds__(64) void fused_main(
    const float* __restrict__ Q, const float* __restrict__ K,
    const float* __restrict__ SQ, const float* __restrict__ SK,
    const float* __restrict__ ROI, const float* __restrict__ W,
    const float* __restrict__ Bb, float* __restrict__ out,
    float* __restrict__ scores)
{
    __shared__ float4 ldsQ[512];   // 64 rows x 8 float4 (32 dims), swizzled
    __shared__ float4 ldsK[512];

    const int lane = threadIdx.x;        // 0..63
    const int p0 = blockIdx.x * 64;      // first pair of this wave
    const int rsub = lane >> 3;          // staging row subgroup (= row & 7)
    const int jcol = lane & 7;           // staging float4 column

    const float4* Q4 = (const float4*)Q;   // pair p occupies f4 [p*64, p*64+64)
    const float4* K4 = (const float4*)K;

    // acc[0..7] = q.Wq_h + k.Wk_h ; acc[8]=q.k ; acc[9]=q.q ; acc[10]=k.k
    float acc[11];
#pragma unroll
    for (int i = 0; i < 11; ++i) acc[i] = 0.0f;

    // Prefetch chunk 0 (each lane: 8 Q float4 + 8 K float4; 8-lane clusters
    // cover 128 B contiguous segments -> full cache lines).
    float4 gq[8], gk[8];
#pragma unroll
    for (int t = 0; t < 8; ++t) {
        const int r = rsub + 8 * t;
        gq[t] = Q4[(size_t)(p0 + r) * 64 + jcol];
        gk[t] = K4[(size_t)(p0 + r) * 64 + jcol];
    }

    for (int c = 0; c < 8; ++c) {
        __syncthreads();                 // previous chunk's LDS reads done
#pragma unroll
        for (int t = 0; t < 8; ++t) {
            const int r = rsub + 8 * t;
            const int a = r * 8 + (jcol ^ rsub);   // swizzle key = r & 7
            ldsQ[a] = gq[t];
            ldsK[a] = gk[t];
        }
        if (c < 7) {                     // prefetch next chunk during compute
#pragma unroll
            for (int t = 0; t < 8; ++t) {
                const int r = rsub + 8 * t;
                gq[t] = Q4[(size_t)(p0 + r) * 64 + (c + 1) * 8 + jcol];
                gk[t] = K4[(size_t)(p0 + r) * 64 + (c + 1) * 8 + jcol];
            }
        }
        __syncthreads();

        // Lane reads its own pair's 32-dim chunk (row = lane), swizzled.
        float4 qc[8], kc[8];
#pragma unroll
        for (int j = 0; j < 8; ++j) {
            const int a = lane * 8 + (j ^ (lane & 7));
            qc[j] = ldsQ[a];
            kc[j] = ldsK[a];
        }

        // Cosine partials (3 independent chains).
#pragma unroll
        for (int j = 0; j < 8; ++j) {
            acc[8]  += dot4(qc[j], kc[j]);
            acc[9]  += dot4(qc[j], qc[j]);
            acc[10] += dot4(kc[j], kc[j]);
        }
        // Head projections; W addresses are wave-uniform -> s_load operands.
#pragma unroll
        for (int h = 0; h < NH; ++h) {
            const float4* wq = (const float4*)(W + h * LEN + c * 32);
            const float4* wk = (const float4*)(W + h * LEN + 256 + c * 32);
            float a0 = 0.0f;
#pragma unroll
            for (int j = 0; j < 8; ++j) {
                a0 += dot4(qc[j], wq[j]);
                a0 += dot4(kc[j], wk[j]);
            }
            acc[h] += a0;
        }
    }

    // Epilogue: lane's pair p = p0 + lane. All stores coalesced.
    const int p = p0 + lane;
    const float qn = fmaxf(sqrtf(acc[9]),  EPSV);
    const float kn = fmaxf(sqrtf(acc[10]), EPSV);
    scores[p] = fmaxf(acc[8] / (qn * kn), 0.0f);

    const float2 sq = ((const float2*)SQ)[p];
    const float2 sk = ((const float2*)SK)[p];
    const float roi = ROI[p];
    float ov[NH];
#pragma unroll
    for (int h = 0; h < NH; ++h) {
        const float4 wt = *(const float4*)(W + h * LEN + 512);  // uniform
        float x = acc[h] + sq.x * wt.x + sq.y * wt.y
                         + sk.x * wt.z + sk.y * wt.w + Bb[h];
        ov[h] = roi / (1.0f + __expf(-x));
    }
    ((float4*)out)[(size_t)p * 2]     = make_float4(ov[0], ov[1], ov[2], ov[3]);
    ((float4*)out)[(size_t)p * 2 + 1] = make_float4(ov[4], ov[5], ov[6], ov[7]);
}

// Kernel 2: zero the indicator (ws is poisoned 0xAA before each launch).
__global__ void zero_ind(float* __restrict__ ind) {
    ind[threadIdx.x] = 0.0f;
}

// Kernel 3: per (b,q) row, extract top-k indices (stable: ties -> lower
// index) and mark ind[idx] = 1.0. One wave per row.
__global__ __launch_bounds__(64) void topk_kernel(
    const float* __restrict__ scores, float* __restrict__ ind,
    const int* __restrict__ node_num)
{
    const int row = blockIdx.x;
    const int lane = threadIdx.x;
    const float4 v4 = *(const float4*)(scores + row * NN + lane * 4);
    float v[4] = {v4.x, v4.y, v4.z, v4.w};

    int Kk = node_num[0];
    if (Kk > NN) Kk = NN;
    for (int t = 0; t < Kk; t++) {
        float mv = v[0];
        int mi = lane * 4;
#pragma unroll
        for (int j = 1; j < 4; j++) {
            if (v[j] > mv) { mv = v[j]; mi = lane * 4 + j; }
        }
        for (int off = 32; off > 0; off >>= 1) {
            const float ov = __shfl_xor(mv, off, 64);
            const int   oi = __shfl_xor(mi, off, 64);
            if (ov > mv || (ov == mv && oi < mi)) { mv = ov; mi = oi; }
        }
        if (lane == 0) ind[mi] = 1.0f;             // idempotent 1.0 store
        if ((mi >> 2) == lane) v[mi & 3] = -1.0f;  // remove (scores >= 0)
    }
}

// Kernel 4: out *= ind[k]; float4 over out (element e: k = (e/8)%256).
__global__ __launch_bounds__(256) void apply_ind_kernel(
    float* __restrict__ out, const float* __restrict__ ind)
{
    const int i = blockIdx.x * blockDim.x + threadIdx.x;  // float4 index
    float4 v = ((float4*)out)[i];
    const float m = ind[(i >> 1) & (NN - 1)];
    v.x *= m; v.y *= m; v.z *= m; v.w *= m;
    ((float4*)out)[i] = v;
}

extern "C" void kernel_launch(void* const* d_in, const int* in_sizes, int n_in,
                              void* d_out, int out_size, void* d_ws, size_t ws_size,
                              hipStream_t stream)
{
    const float* Q   = (const float*)d_in[0];
    const float* K   = (const float*)d_in[1];
    const float* SQ  = (const float*)d_in[2];
    const float* SK  = (const float*)d_in[3];
    const float* ROI = (const float*)d_in[4];
    const float* W   = (const float*)d_in[5];
    const float* Bb  = (const float*)d_in[6];
    const int* node_num = (const int*)d_in[7];

    float* out = (float*)d_out;
    float* scores = (float*)d_ws;          // NPAIR floats (512 KB)
    float* ind = scores + NPAIR;           // NN floats

    fused_main<<<NPAIR / 64, 64, 0, stream>>>(Q, K, SQ, SK, ROI, W, Bb, out, scores);
    zero_ind<<<1, 256, 0, stream>>>(ind);
    topk_kernel<<<NROWS, 64, 0, stream>>>(scores, ind, node_num);
    apply_ind_kernel<<<out_size / 4 / 256, 256, 0, stream>>>(out, ind);
}